// Round 12
// baseline (309.240 us; speedup 1.0000x reference)
//
#include <hip/hip_runtime.h>

typedef __attribute__((ext_vector_type(4))) float f32x4;
typedef __attribute__((ext_vector_type(8))) short bf16x8;
typedef __attribute__((ext_vector_type(4))) short s16x4;
typedef __attribute__((ext_vector_type(4))) unsigned u32x4;
typedef unsigned short u16;

#define GLOAD_LDS16(g, l)                                                      \
  __builtin_amdgcn_global_load_lds(                                            \
      (__attribute__((address_space(1))) const void*)(g),                      \
      (__attribute__((address_space(3))) void*)(l), 16, 0, 0)

static __device__ __forceinline__ u16 f2b(float f) {
  unsigned u = __builtin_bit_cast(unsigned, f);
  unsigned r = (u + 0x7fffu + ((u >> 16) & 1u)) >> 16;
  return (u16)r;
}

// packed f32x2 -> bf16x2 (RNE, matches f2b); no builtin on gfx950
static __device__ __forceinline__ unsigned pk2(float lo, float hi) {
  unsigned r;
  asm("v_cvt_pk_bf16_f32 %0, %1, %2" : "=v"(r) : "v"(lo), "v"(hi));
  return r;
}

static __device__ __forceinline__ f32x4 mfma16(bf16x8 a, bf16x8 b, f32x4 c) {
  return __builtin_amdgcn_mfma_f32_16x16x32_bf16(a, b, c, 0, 0, 0);
}

// bank swizzle: chunk' = chunk ^ fsw(row)
static __device__ __forceinline__ int fsw(int row) {
  return (row & 7) ^ ((row & 8) >> 1);
}

// ---------------- f32 -> bf16 convert ----------------
__global__ __launch_bounds__(256) void cvt_bf16(const float* __restrict__ in,
                                                u16* __restrict__ out, int n4) {
  int i = blockIdx.x * 256 + threadIdx.x;
  int stride = gridDim.x * 256;
  for (; i < n4; i += stride) {
    float4 v = ((const float4*)in)[i];
    s16x4 o;
    o[0] = (short)f2b(v.x);
    o[1] = (short)f2b(v.y);
    o[2] = (short)f2b(v.z);
    o[3] = (short)f2b(v.w);
    ((s16x4*)out)[i] = o;
  }
}

// 4 weight matrices in one launch (blockIdx.y selects)
__global__ __launch_bounds__(256) void cvt_w4(const float* __restrict__ w0,
                                              const float* __restrict__ w1,
                                              const float* __restrict__ w2,
                                              const float* __restrict__ w3,
                                              u16* __restrict__ o0,
                                              u16* __restrict__ o1,
                                              u16* __restrict__ o2,
                                              u16* __restrict__ o3) {
  int y = blockIdx.y;
  const float* in = (y == 0) ? w0 : (y == 1) ? w1 : (y == 2) ? w2 : w3;
  u16* out = (y == 0) ? o0 : (y == 1) ? o1 : (y == 2) ? o2 : o3;
  const int n4 = 262144;
  int i = blockIdx.x * 256 + threadIdx.x;
  int stride = gridDim.x * 256;
  for (; i < n4; i += stride) {
    float4 v = ((const float4*)in)[i];
    s16x4 o;
    o[0] = (short)f2b(v.x);
    o[1] = (short)f2b(v.y);
    o[2] = (short)f2b(v.z);
    o[3] = (short)f2b(v.w);
    ((s16x4*)out)[i] = o;
  }
}

// ---------------- fused QKV GEMM (z=0:Q scaled, z=1:K, z=2:V transposed) -----
#define QSCALE 0.0450842200278f
__global__ __launch_bounds__(256) void gemm_qkv3(
    const u16* __restrict__ xb, const u16* __restrict__ eb,
    const u16* __restrict__ Wqb, const u16* __restrict__ Wkb,
    const u16* __restrict__ Wvb, const float* __restrict__ bq,
    const float* __restrict__ bk, const float* __restrict__ bv,
    u16* __restrict__ Qd, u16* __restrict__ Kd, u16* __restrict__ Vtd) {
  __shared__ __align__(16) u16 As[128 * 32];
  __shared__ __align__(16) u16 Bs[128 * 32];
  const int K = 1024;
  int z = blockIdx.z;
  const u16* A = (z == 0) ? xb : eb;
  const u16* W = (z == 0) ? Wqb : (z == 1) ? Wkb : Wvb;
  const float* bias = (z == 0) ? bq : (z == 1) ? bk : bv;

  int tid = threadIdx.x;
  int w = tid >> 6, lane = tid & 63;
  int wr = w >> 1, wc = w & 1;
  int r16 = lane & 15, c4 = lane >> 4;
  int m0 = blockIdx.y * 128, n0 = blockIdx.x * 128;
  int srow = tid >> 2;
  int scol = (tid & 3) * 8;

  f32x4 acc[4][4] = {};

  const u16* ga0 = A + (size_t)(m0 + srow) * K + scol;
  const u16* gb0 = W + (size_t)(n0 + srow) * K + scol;
  char* asb = (char*)As + w * 1024;
  char* bsb = (char*)Bs + w * 1024;

  for (int k0 = 0; k0 < K; k0 += 32) {
    GLOAD_LDS16(ga0 + k0, asb);
    GLOAD_LDS16(ga0 + 64 * K + k0, asb + 4096);
    GLOAD_LDS16(gb0 + k0, bsb);
    GLOAD_LDS16(gb0 + 64 * K + k0, bsb + 4096);
    __syncthreads();
    bf16x8 af[4], bfr[4];
#pragma unroll
    for (int i = 0; i < 4; ++i)
      af[i] = *(const bf16x8*)(As + (wr * 64 + i * 16 + r16) * 32 + c4 * 8);
#pragma unroll
    for (int j = 0; j < 4; ++j)
      bfr[j] = *(const bf16x8*)(Bs + (wc * 64 + j * 16 + r16) * 32 + c4 * 8);
#pragma unroll
    for (int i = 0; i < 4; ++i)
#pragma unroll
      for (int j = 0; j < 4; ++j) acc[i][j] = mfma16(af[i], bfr[j], acc[i][j]);
    __syncthreads();
  }

  if (z < 2) {
    float oscale = (z == 0) ? QSCALE : 1.0f;
    u16* dst = (z == 0) ? Qd : Kd;
#pragma unroll
    for (int i = 0; i < 4; ++i) {
      int m = m0 + wr * 64 + i * 16 + c4 * 4;
      int b = m >> 11, s = m & 2047;
#pragma unroll
      for (int j = 0; j < 4; ++j) {
        int n = n0 + wc * 64 + j * 16 + r16;
        int h = n >> 6, d = n & 63;
        float bv = bias[n];
        u16* dp = dst + (((size_t)(b * 16 + h) * 2048 + s) * 64 + d);
#pragma unroll
        for (int r = 0; r < 4; ++r)
          dp[(size_t)r * 64] = f2b((acc[i][j][r] + bv) * oscale);
      }
    }
  } else {
#pragma unroll
    for (int i = 0; i < 4; ++i) {
      int m = m0 + wr * 64 + i * 16 + c4 * 4;
      int b = m >> 11, s = m & 2047;
#pragma unroll
      for (int j = 0; j < 4; ++j) {
        int n = n0 + wc * 64 + j * 16 + r16;
        int h = n >> 6, d = n & 63;
        float bv = bias[n];
        s16x4 o4;
#pragma unroll
        for (int r = 0; r < 4; ++r) o4[r] = (short)f2b(acc[i][j][r] + bv);
        *(s16x4*)(Vtd + ((size_t)((b * 16 + h) * 64 + d)) * 2048 + s) = o4;
      }
    }
  }
}

// ---------------- out-proj GEMM: Y = ctx * Wo^T + bo + X (f32) ----------------
__global__ __launch_bounds__(256) void gemm_out(const u16* __restrict__ A,
                                                const u16* __restrict__ W,
                                                const float* __restrict__ bias,
                                                const float* __restrict__ X,
                                                float* __restrict__ Y) {
  __shared__ __align__(16) u16 As[128 * 32];
  __shared__ __align__(16) u16 Bs[128 * 32];
  const int K = 1024;
  int tid = threadIdx.x;
  int w = tid >> 6, lane = tid & 63;
  int wr = w >> 1, wc = w & 1;
  int r16 = lane & 15, c4 = lane >> 4;
  int m0 = blockIdx.y * 128, n0 = blockIdx.x * 128;
  int srow = tid >> 2;
  int scol = (tid & 3) * 8;

  f32x4 acc[4][4] = {};

  const u16* ga0 = A + (size_t)(m0 + srow) * K + scol;
  const u16* gb0 = W + (size_t)(n0 + srow) * K + scol;
  char* asb = (char*)As + w * 1024;
  char* bsb = (char*)Bs + w * 1024;

  for (int k0 = 0; k0 < K; k0 += 32) {
    GLOAD_LDS16(ga0 + k0, asb);
    GLOAD_LDS16(ga0 + 64 * K + k0, asb + 4096);
    GLOAD_LDS16(gb0 + k0, bsb);
    GLOAD_LDS16(gb0 + 64 * K + k0, bsb + 4096);
    __syncthreads();
    bf16x8 af[4], bfr[4];
#pragma unroll
    for (int i = 0; i < 4; ++i)
      af[i] = *(const bf16x8*)(As + (wr * 64 + i * 16 + r16) * 32 + c4 * 8);
#pragma unroll
    for (int j = 0; j < 4; ++j)
      bfr[j] = *(const bf16x8*)(Bs + (wc * 64 + j * 16 + r16) * 32 + c4 * 8);
#pragma unroll
    for (int i = 0; i < 4; ++i)
#pragma unroll
      for (int j = 0; j < 4; ++j) acc[i][j] = mfma16(af[i], bfr[j], acc[i][j]);
    __syncthreads();
  }

#pragma unroll
  for (int i = 0; i < 4; ++i) {
    int m = m0 + wr * 64 + i * 16 + c4 * 4;
#pragma unroll
    for (int j = 0; j < 4; ++j) {
      int n = n0 + wc * 64 + j * 16 + r16;
      float bv = bias[n];
#pragma unroll
      for (int r = 0; r < 4; ++r) {
        size_t idx = (size_t)(m + r) * 1024 + n;
        Y[idx] = acc[i][j][r] + bv + X[idx];
      }
    }
  }
}

// ---------------- sum kernel: nls[bh][q] = -log2(sum_kv exp2(S)) -------------
// GEMM-shaped: 128 q/block (4 waves x 32 q) share each staged K tile -> K
// L2 traffic and LDS reads per unit work halve vs the fused pass-1, and no
// store stream contends. Pipeline = R11's verified triple-buffer K, 2 ahead,
// vmcnt(2). Fragment math = R8's verified 32q/wave pass-1.
__global__ __launch_bounds__(256, 4) void sum_k(const u16* __restrict__ Q,
                                                const u16* __restrict__ Kg,
                                                float* __restrict__ nlsbuf) {
  __shared__ __align__(16) u16 Klds[3][64 * 64];

  int tid = threadIdx.x;
  int w = tid >> 6, lane = tid & 63;
  int r16 = lane & 15, c4 = lane >> 4;
  int id = blockIdx.x;
  int bh = id & 31, qt = id >> 5;
  int q0 = qt * 128 + w * 32;

  const u16* Qp = Q + ((size_t)bh * 2048 + q0) * 64;
  const u16* Kp = Kg + (size_t)bh * 2048 * 64;

  bf16x8 qf[2][2];
#pragma unroll
  for (int hh = 0; hh < 2; ++hh)
#pragma unroll
    for (int ch = 0; ch < 2; ++ch)
      qf[hh][ch] = *(const bf16x8*)(Qp + (size_t)(hh * 16 + r16) * 64 +
                                    ch * 32 + c4 * 8);

  int perm0 = ((r16 >> 2) << 3) + (r16 & 3);
  int srow0 = w * 8 + (lane >> 3);
  int sc = lane & 7;

#define STAGE_K(bufi, kv)                                                      \
  {                                                                            \
    _Pragma("unroll") for (int i = 0; i < 2; ++i) {                            \
      int row = i * 32 + srow0;                                                \
      int ch = sc ^ fsw(row);                                                  \
      GLOAD_LDS16(Kp + (size_t)(((kv) & 2047) + row) * 64 + ch * 8,            \
                  (u16*)&Klds[bufi][0] + w * 512 + i * 2048);                  \
    }                                                                          \
  }
#define LDSF(base, row, chunk)                                                 \
  (*(const bf16x8*)((base) + (row) * 64 + (((chunk) ^ fsw(row)) << 3)))
#define WAIT_BAR(n)                                                            \
  {                                                                            \
    asm volatile("s_waitcnt vmcnt(" #n ")" ::: "memory");                      \
    __builtin_amdgcn_s_barrier();                                              \
  }

  float sumA = 0.f, sumB = 0.f;
  STAGE_K(0, 0);
  STAGE_K(1, 64);
  WAIT_BAR(2);  // K(0) done; K(1) in flight
  {
    int wbuf = 2, rbuf = 0;
    for (int kv0 = 0; kv0 < 2048; kv0 += 64) {
      STAGE_K(wbuf, kv0 + 128);
      const u16* Kb = &Klds[rbuf][0];
#pragma unroll
      for (int s = 0; s < 2; ++s) {
        int ra = s * 32 + perm0;
        bf16x8 k00 = LDSF(Kb, ra, c4);
        bf16x8 k01 = LDSF(Kb, ra, c4 + 4);
        bf16x8 k10 = LDSF(Kb, ra + 4, c4);
        bf16x8 k11 = LDSF(Kb, ra + 4, c4 + 4);
        f32x4 s0A = {}, s1A = {}, s0B = {}, s1B = {};
        __builtin_amdgcn_s_setprio(1);
        s0A = mfma16(k00, qf[0][0], s0A);
        s0A = mfma16(k01, qf[0][1], s0A);
        s1A = mfma16(k10, qf[0][0], s1A);
        s1A = mfma16(k11, qf[0][1], s1A);
        s0B = mfma16(k00, qf[1][0], s0B);
        s0B = mfma16(k01, qf[1][1], s0B);
        s1B = mfma16(k10, qf[1][0], s1B);
        s1B = mfma16(k11, qf[1][1], s1B);
        __builtin_amdgcn_s_setprio(0);
#pragma unroll
        for (int r = 0; r < 4; ++r) {
          sumA +=
              __builtin_amdgcn_exp2f(s0A[r]) + __builtin_amdgcn_exp2f(s1A[r]);
          sumB +=
              __builtin_amdgcn_exp2f(s0B[r]) + __builtin_amdgcn_exp2f(s1B[r]);
        }
      }
      WAIT_BAR(2);  // retire K(t+1); keep K(t+2) in flight
      wbuf = (wbuf == 2) ? 0 : wbuf + 1;
      rbuf = (rbuf == 2) ? 0 : rbuf + 1;
    }
  }
  sumA += __shfl_xor(sumA, 16, 64);
  sumA += __shfl_xor(sumA, 32, 64);
  sumB += __shfl_xor(sumB, 16, 64);
  sumB += __shfl_xor(sumB, 32, 64);
  if (c4 == 0) {
    nlsbuf[(size_t)bh * 2048 + q0 + r16] = -__log2f(sumA);
    nlsbuf[(size_t)bh * 2048 + q0 + 16 + r16] = -__log2f(sumB);
  }
#undef STAGE_K
#undef LDSF
#undef WAIT_BAR
}

// ---------------- PV kernel: P write + ctx = P*V (R11 pass-2 verbatim) ------
// Block = 4 waves x 16 q; 1024 blocks, 4 blocks/CU (LDS 40KB). K triple-
// buffered 2 ahead, V double-buffered 1 ahead, vmcnt(6) end-of-step wait
// (retires K(t+1)+V(t+1)+stores(t-1); keeps K(t+2)+stores(t) in flight).
// nls loaded from sum_k's output.
__global__ __launch_bounds__(256, 4) void attn_pv(const u16* __restrict__ Q,
                                                  const u16* __restrict__ Kg,
                                                  const u16* __restrict__ Vt,
                                                  const float* __restrict__ nlsbuf,
                                                  float* __restrict__ attnw,
                                                  u16* __restrict__ ctx) {
  __shared__ __align__(16) u16 Klds[3][64 * 64];
  __shared__ __align__(16) u16 Vlds[2][64 * 64];

  int tid = threadIdx.x;
  int w = tid >> 6, lane = tid & 63;
  int r16 = lane & 15, c4 = lane >> 4;
  int id = blockIdx.x;
  int bh = id & 31, qt = id >> 5;
  int b = bh >> 4, h = bh & 15;
  int q0 = qt * 64 + w * 16;

  const u16* Qp = Q + ((size_t)bh * 2048 + q0) * 64;
  const u16* Kp = Kg + (size_t)bh * 2048 * 64;
  const u16* Vp = Vt + (size_t)bh * 64 * 2048;

  bf16x8 qf0 = *(const bf16x8*)(Qp + (size_t)r16 * 64 + c4 * 8);
  bf16x8 qf1 = *(const bf16x8*)(Qp + (size_t)r16 * 64 + 32 + c4 * 8);
  float nls = nlsbuf[(size_t)bh * 2048 + q0 + r16];

  int perm0 = ((r16 >> 2) << 3) + (r16 & 3);
  int srow0 = w * 8 + (lane >> 3);
  int sc = lane & 7;

#define STAGE_K(bufi, kv)                                                      \
  {                                                                            \
    _Pragma("unroll") for (int i = 0; i < 2; ++i) {                            \
      int row = i * 32 + srow0;                                                \
      int ch = sc ^ fsw(row);                                                  \
      GLOAD_LDS16(Kp + (size_t)(((kv) & 2047) + row) * 64 + ch * 8,            \
                  (u16*)&Klds[bufi][0] + w * 512 + i * 2048);                  \
    }                                                                          \
  }
#define STAGE_V(bufi, kv)                                                      \
  {                                                                            \
    _Pragma("unroll") for (int i = 0; i < 2; ++i) {                            \
      int row = i * 32 + srow0;                                                \
      int ch = sc ^ fsw(row);                                                  \
      GLOAD_LDS16(Vp + (size_t)row * 2048 + ((kv) & 2047) + ch * 8,            \
                  (u16*)&Vlds[bufi][0] + w * 512 + i * 2048);                  \
    }                                                                          \
  }
#define LDSF(base, row, chunk)                                                 \
  (*(const bf16x8*)((base) + (row) * 64 + (((chunk) ^ fsw(row)) << 3)))
#define WAIT_BAR(n)                                                            \
  {                                                                            \
    asm volatile("s_waitcnt vmcnt(" #n ")" ::: "memory");                      \
    __builtin_amdgcn_s_barrier();                                              \
  }

  f32x4 o[4] = {};
  float* ap = attnw + ((size_t)bh * 2048 + q0 + r16) * 2048;
  STAGE_V(0, 0);
  STAGE_K(0, 0);
  STAGE_K(1, 64);
  WAIT_BAR(2);  // V(0)+K(0) done; K(1) in flight
  {
    int wbuf = 2, rbuf = 0;
    int t = 0;
    for (int kv0 = 0; kv0 < 2048; kv0 += 64, ++t) {
      STAGE_V((t + 1) & 1, kv0 + 64);  // V(t+1), issued before K so it's older
      STAGE_K(wbuf, kv0 + 128);
      const u16* Kb = &Klds[rbuf][0];
      const u16* Vb = &Vlds[t & 1][0];
#pragma unroll
      for (int s = 0; s < 2; ++s) {
        int ra = s * 32 + perm0;
        bf16x8 k00 = LDSF(Kb, ra, c4);
        bf16x8 k01 = LDSF(Kb, ra, c4 + 4);
        bf16x8 k10 = LDSF(Kb, ra + 4, c4);
        bf16x8 k11 = LDSF(Kb, ra + 4, c4 + 4);
        f32x4 s0 = {}, s1 = {};
        __builtin_amdgcn_s_setprio(1);
        s0 = mfma16(k00, qf0, s0);
        s0 = mfma16(k01, qf1, s0);
        s1 = mfma16(k10, qf0, s1);
        s1 = mfma16(k11, qf1, s1);
        __builtin_amdgcn_s_setprio(0);
        f32x4 p0, p1;
#pragma unroll
        for (int r = 0; r < 4; ++r) {
          p0[r] = __builtin_amdgcn_exp2f(s0[r] + nls);
          p1[r] = __builtin_amdgcn_exp2f(s1[r] + nls);
        }
        u32x4 pk;
        pk[0] = pk2(p0[0], p0[1]);
        pk[1] = pk2(p0[2], p0[3]);
        pk[2] = pk2(p1[0], p1[1]);
        pk[3] = pk2(p1[2], p1[3]);
        bf16x8 pf = __builtin_bit_cast(bf16x8, pk);
        bf16x8 v0 = LDSF(Vb, 0 * 16 + r16, s * 4 + c4);
        bf16x8 v1 = LDSF(Vb, 1 * 16 + r16, s * 4 + c4);
        bf16x8 v2 = LDSF(Vb, 2 * 16 + r16, s * 4 + c4);
        bf16x8 v3 = LDSF(Vb, 3 * 16 + r16, s * 4 + c4);
        __builtin_amdgcn_s_setprio(1);
        o[0] = mfma16(pf, v0, o[0]);
        o[1] = mfma16(pf, v1, o[1]);
        o[2] = mfma16(pf, v2, o[2]);
        o[3] = mfma16(pf, v3, o[3]);
        __builtin_amdgcn_s_setprio(0);
        int kvc = kv0 + s * 32 + c4 * 8;
        *(f32x4*)(ap + kvc) = p0;
        *(f32x4*)(ap + kvc + 4) = p1;
      }
      WAIT_BAR(6);  // retire K(t+1)+V(t+1)+stores(t-1); keep K(t+2)+stores(t)
      wbuf = (wbuf == 2) ? 0 : wbuf + 1;
      rbuf = (rbuf == 2) ? 0 : rbuf + 1;
    }
  }

#pragma unroll
  for (int dt = 0; dt < 4; ++dt)
#pragma unroll
    for (int r = 0; r < 4; ++r)
      ctx[((size_t)(b * 2048 + q0 + c4 * 4 + r)) * 1024 + h * 64 + dt * 16 +
          r16] = f2b(o[dt][r]);
#undef STAGE_K
#undef STAGE_V
#undef LDSF
#undef WAIT_BAR
}

// ---------------- LayerNorm over last dim (1024), wave per row ----------------
__global__ __launch_bounds__(256) void ln_k(const float* __restrict__ Y,
                                            const float* __restrict__ gamma,
                                            const float* __restrict__ beta,
                                            float* __restrict__ out) {
  int row = blockIdx.x * 4 + (threadIdx.x >> 6);
  int lane = threadIdx.x & 63;
  const float* yr = Y + (size_t)row * 1024;
  float4 v[4];
  float sum = 0.f, sq = 0.f;
#pragma unroll
  for (int i = 0; i < 4; ++i) {
    v[i] = *(const float4*)(yr + i * 256 + lane * 4);
    sum += v[i].x + v[i].y + v[i].z + v[i].w;
    sq += v[i].x * v[i].x + v[i].y * v[i].y + v[i].z * v[i].z + v[i].w * v[i].w;
  }
#pragma unroll
  for (int m = 1; m < 64; m <<= 1) {
    sum += __shfl_xor(sum, m, 64);
    sq += __shfl_xor(sq, m, 64);
  }
  float mu = sum * (1.f / 1024.f);
  float var = sq * (1.f / 1024.f) - mu * mu;
  float rs = rsqrtf(var + 1e-5f);
  float* orow = out + (size_t)row * 1024;
#pragma unroll
  for (int i = 0; i < 4; ++i) {
    int c = i * 256 + lane * 4;
    float4 g = *(const float4*)(gamma + c);
    float4 be = *(const float4*)(beta + c);
    float4 o;
    o.x = (v[i].x - mu) * rs * g.x + be.x;
    o.y = (v[i].y - mu) * rs * g.y + be.y;
    o.z = (v[i].z - mu) * rs * g.z + be.z;
    o.w = (v[i].w - mu) * rs * g.w + be.w;
    *(float4*)(orow + c) = o;
  }
}

extern "C" void kernel_launch(void* const* d_in, const int* in_sizes, int n_in,
                              void* d_out, int out_size, void* d_ws,
                              size_t ws_size, hipStream_t stream) {
  const float* x = (const float*)d_in[0];
  const float* enc = (const float*)d_in[1];
  const float* Wq = (const float*)d_in[2];
  const float* bq = (const float*)d_in[3];
  const float* Wk = (const float*)d_in[4];
  const float* bk = (const float*)d_in[5];
  const float* Wv = (const float*)d_in[6];
  const float* bv = (const float*)d_in[7];
  const float* Wo = (const float*)d_in[8];
  const float* bo = (const float*)d_in[9];
  const float* gamma = (const float*)d_in[10];
  const float* beta = (const float*)d_in[11];

  float* out = (float*)d_out;
  float* attnw = out + (size_t)4194304;  // 2*2048*1024

  char* ws = (char*)d_ws;
  u16* xb = (u16*)(ws + (size_t)0);
  u16* eb = (u16*)(ws + ((size_t)8 << 20));
  u16* Wqb = (u16*)(ws + ((size_t)16 << 20));
  u16* Wkb = (u16*)(ws + ((size_t)18 << 20));
  u16* Wvb = (u16*)(ws + ((size_t)20 << 20));
  u16* Wob = (u16*)(ws + ((size_t)22 << 20));
  u16* Qws = (u16*)(ws + ((size_t)24 << 20));
  u16* Kws = (u16*)(ws + ((size_t)32 << 20));
  u16* Vt = (u16*)(ws + ((size_t)48 << 20));
  u16* ctx = (u16*)(ws + ((size_t)40 << 20));
  float* nlsbuf = (float*)(ws + ((size_t)56 << 20));  // 64K floats = 256 KB
  float* Yws = (float*)(ws + (size_t)0);  // reuse xb/eb (dead after gemms)

  cvt_bf16<<<dim3(1024), 256, 0, stream>>>(x, xb, 1048576);
  cvt_bf16<<<dim3(1024), 256, 0, stream>>>(enc, eb, 1048576);
  cvt_w4<<<dim3(256, 4), 256, 0, stream>>>(Wq, Wk, Wv, Wo, Wqb, Wkb, Wvb, Wob);

  gemm_qkv3<<<dim3(8, 32, 3), 256, 0, stream>>>(xb, eb, Wqb, Wkb, Wvb, bq, bk,
                                                bv, Qws, Kws, Vt);

  sum_k<<<dim3(512), 256, 0, stream>>>(Qws, Kws, nlsbuf);
  attn_pv<<<dim3(1024), 256, 0, stream>>>(Qws, Kws, Vt, nlsbuf, attnw, ctx);

  gemm_out<<<dim3(8, 32), 256, 0, stream>>>(ctx, Wob, bo, x, Yws);

  ln_k<<<dim3(1024), 256, 0, stream>>>(Yws, gamma, beta, out);
}

// Round 13
// 259.858 us; speedup vs baseline: 1.1900x; 1.1900x over previous
//
#include <hip/hip_runtime.h>

typedef __attribute__((ext_vector_type(4))) float f32x4;
typedef __attribute__((ext_vector_type(8))) short bf16x8;
typedef __attribute__((ext_vector_type(4))) short s16x4;
typedef __attribute__((ext_vector_type(4))) unsigned u32x4;
typedef unsigned short u16;

#define GLOAD_LDS16(g, l)                                                      \
  __builtin_amdgcn_global_load_lds(                                            \
      (__attribute__((address_space(1))) const void*)(g),                      \
      (__attribute__((address_space(3))) void*)(l), 16, 0, 0)

static __device__ __forceinline__ u16 f2b(float f) {
  unsigned u = __builtin_bit_cast(unsigned, f);
  unsigned r = (u + 0x7fffu + ((u >> 16) & 1u)) >> 16;
  return (u16)r;
}

// packed f32x2 -> bf16x2 (RNE, matches f2b); no builtin on gfx950
static __device__ __forceinline__ unsigned pk2(float lo, float hi) {
  unsigned r;
  asm("v_cvt_pk_bf16_f32 %0, %1, %2" : "=v"(r) : "v"(lo), "v"(hi));
  return r;
}

static __device__ __forceinline__ f32x4 mfma16(bf16x8 a, bf16x8 b, f32x4 c) {
  return __builtin_amdgcn_mfma_f32_16x16x32_bf16(a, b, c, 0, 0, 0);
}

// bank swizzle: chunk' = chunk ^ fsw(row)
static __device__ __forceinline__ int fsw(int row) {
  return (row & 7) ^ ((row & 8) >> 1);
}

// ---------------- f32 -> bf16 convert ----------------
__global__ __launch_bounds__(256) void cvt_bf16(const float* __restrict__ in,
                                                u16* __restrict__ out, int n4) {
  int i = blockIdx.x * 256 + threadIdx.x;
  int stride = gridDim.x * 256;
  for (; i < n4; i += stride) {
    float4 v = ((const float4*)in)[i];
    s16x4 o;
    o[0] = (short)f2b(v.x);
    o[1] = (short)f2b(v.y);
    o[2] = (short)f2b(v.z);
    o[3] = (short)f2b(v.w);
    ((s16x4*)out)[i] = o;
  }
}

// 4 weight matrices in one launch (blockIdx.y selects)
__global__ __launch_bounds__(256) void cvt_w4(const float* __restrict__ w0,
                                              const float* __restrict__ w1,
                                              const float* __restrict__ w2,
                                              const float* __restrict__ w3,
                                              u16* __restrict__ o0,
                                              u16* __restrict__ o1,
                                              u16* __restrict__ o2,
                                              u16* __restrict__ o3) {
  int y = blockIdx.y;
  const float* in = (y == 0) ? w0 : (y == 1) ? w1 : (y == 2) ? w2 : w3;
  u16* out = (y == 0) ? o0 : (y == 1) ? o1 : (y == 2) ? o2 : o3;
  const int n4 = 262144;
  int i = blockIdx.x * 256 + threadIdx.x;
  int stride = gridDim.x * 256;
  for (; i < n4; i += stride) {
    float4 v = ((const float4*)in)[i];
    s16x4 o;
    o[0] = (short)f2b(v.x);
    o[1] = (short)f2b(v.y);
    o[2] = (short)f2b(v.z);
    o[3] = (short)f2b(v.w);
    ((s16x4*)out)[i] = o;
  }
}

// ---------------- fused QKV GEMM (z=0:Q scaled, z=1:K, z=2:V transposed) -----
#define QSCALE 0.0450842200278f
__global__ __launch_bounds__(256) void gemm_qkv3(
    const u16* __restrict__ xb, const u16* __restrict__ eb,
    const u16* __restrict__ Wqb, const u16* __restrict__ Wkb,
    const u16* __restrict__ Wvb, const float* __restrict__ bq,
    const float* __restrict__ bk, const float* __restrict__ bv,
    u16* __restrict__ Qd, u16* __restrict__ Kd, u16* __restrict__ Vtd) {
  __shared__ __align__(16) u16 As[128 * 32];
  __shared__ __align__(16) u16 Bs[128 * 32];
  const int K = 1024;
  int z = blockIdx.z;
  const u16* A = (z == 0) ? xb : eb;
  const u16* W = (z == 0) ? Wqb : (z == 1) ? Wkb : Wvb;
  const float* bias = (z == 0) ? bq : (z == 1) ? bk : bv;

  int tid = threadIdx.x;
  int w = tid >> 6, lane = tid & 63;
  int wr = w >> 1, wc = w & 1;
  int r16 = lane & 15, c4 = lane >> 4;
  int m0 = blockIdx.y * 128, n0 = blockIdx.x * 128;
  int srow = tid >> 2;
  int scol = (tid & 3) * 8;

  f32x4 acc[4][4] = {};

  const u16* ga0 = A + (size_t)(m0 + srow) * K + scol;
  const u16* gb0 = W + (size_t)(n0 + srow) * K + scol;
  char* asb = (char*)As + w * 1024;
  char* bsb = (char*)Bs + w * 1024;

  for (int k0 = 0; k0 < K; k0 += 32) {
    GLOAD_LDS16(ga0 + k0, asb);
    GLOAD_LDS16(ga0 + 64 * K + k0, asb + 4096);
    GLOAD_LDS16(gb0 + k0, bsb);
    GLOAD_LDS16(gb0 + 64 * K + k0, bsb + 4096);
    __syncthreads();
    bf16x8 af[4], bfr[4];
#pragma unroll
    for (int i = 0; i < 4; ++i)
      af[i] = *(const bf16x8*)(As + (wr * 64 + i * 16 + r16) * 32 + c4 * 8);
#pragma unroll
    for (int j = 0; j < 4; ++j)
      bfr[j] = *(const bf16x8*)(Bs + (wc * 64 + j * 16 + r16) * 32 + c4 * 8);
#pragma unroll
    for (int i = 0; i < 4; ++i)
#pragma unroll
      for (int j = 0; j < 4; ++j) acc[i][j] = mfma16(af[i], bfr[j], acc[i][j]);
    __syncthreads();
  }

  if (z < 2) {
    float oscale = (z == 0) ? QSCALE : 1.0f;
    u16* dst = (z == 0) ? Qd : Kd;
#pragma unroll
    for (int i = 0; i < 4; ++i) {
      int m = m0 + wr * 64 + i * 16 + c4 * 4;
      int b = m >> 11, s = m & 2047;
#pragma unroll
      for (int j = 0; j < 4; ++j) {
        int n = n0 + wc * 64 + j * 16 + r16;
        int h = n >> 6, d = n & 63;
        float bv = bias[n];
        u16* dp = dst + (((size_t)(b * 16 + h) * 2048 + s) * 64 + d);
#pragma unroll
        for (int r = 0; r < 4; ++r)
          dp[(size_t)r * 64] = f2b((acc[i][j][r] + bv) * oscale);
      }
    }
  } else {
#pragma unroll
    for (int i = 0; i < 4; ++i) {
      int m = m0 + wr * 64 + i * 16 + c4 * 4;
      int b = m >> 11, s = m & 2047;
#pragma unroll
      for (int j = 0; j < 4; ++j) {
        int n = n0 + wc * 64 + j * 16 + r16;
        int h = n >> 6, d = n & 63;
        float bv = bias[n];
        s16x4 o4;
#pragma unroll
        for (int r = 0; r < 4; ++r) o4[r] = (short)f2b(acc[i][j][r] + bv);
        *(s16x4*)(Vtd + ((size_t)((b * 16 + h) * 64 + d)) * 2048 + s) = o4;
      }
    }
  }
}

// ---------------- out-proj GEMM: Y = ctx * Wo^T + bo + X (f32) ----------------
__global__ __launch_bounds__(256) void gemm_out(const u16* __restrict__ A,
                                                const u16* __restrict__ W,
                                                const float* __restrict__ bias,
                                                const float* __restrict__ X,
                                                float* __restrict__ Y) {
  __shared__ __align__(16) u16 As[128 * 32];
  __shared__ __align__(16) u16 Bs[128 * 32];
  const int K = 1024;
  int tid = threadIdx.x;
  int w = tid >> 6, lane = tid & 63;
  int wr = w >> 1, wc = w & 1;
  int r16 = lane & 15, c4 = lane >> 4;
  int m0 = blockIdx.y * 128, n0 = blockIdx.x * 128;
  int srow = tid >> 2;
  int scol = (tid & 3) * 8;

  f32x4 acc[4][4] = {};

  const u16* ga0 = A + (size_t)(m0 + srow) * K + scol;
  const u16* gb0 = W + (size_t)(n0 + srow) * K + scol;
  char* asb = (char*)As + w * 1024;
  char* bsb = (char*)Bs + w * 1024;

  for (int k0 = 0; k0 < K; k0 += 32) {
    GLOAD_LDS16(ga0 + k0, asb);
    GLOAD_LDS16(ga0 + 64 * K + k0, asb + 4096);
    GLOAD_LDS16(gb0 + k0, bsb);
    GLOAD_LDS16(gb0 + 64 * K + k0, bsb + 4096);
    __syncthreads();
    bf16x8 af[4], bfr[4];
#pragma unroll
    for (int i = 0; i < 4; ++i)
      af[i] = *(const bf16x8*)(As + (wr * 64 + i * 16 + r16) * 32 + c4 * 8);
#pragma unroll
    for (int j = 0; j < 4; ++j)
      bfr[j] = *(const bf16x8*)(Bs + (wc * 64 + j * 16 + r16) * 32 + c4 * 8);
#pragma unroll
    for (int i = 0; i < 4; ++i)
#pragma unroll
      for (int j = 0; j < 4; ++j) acc[i][j] = mfma16(af[i], bfr[j], acc[i][j]);
    __syncthreads();
  }

#pragma unroll
  for (int i = 0; i < 4; ++i) {
    int m = m0 + wr * 64 + i * 16 + c4 * 4;
#pragma unroll
    for (int j = 0; j < 4; ++j) {
      int n = n0 + wc * 64 + j * 16 + r16;
      float bv = bias[n];
#pragma unroll
      for (int r = 0; r < 4; ++r) {
        size_t idx = (size_t)(m + r) * 1024 + n;
        Y[idx] = acc[i][j][r] + bv + X[idx];
      }
    }
  }
}

// ---------------- fused attention v13: kv-parallel wave groups ---------------
// Block = 8 waves = 2 groups x 4 waves x 16 q (same 64 q rows). Group g sweeps
// kv half [g*1024, g*1024+1024) with its OWN K (triple) / V (double) buffers,
// so each pass is 16 barrier steps instead of 32 — halves the serial chain
// that 9 flat schedule variants identified as the floor. Per-wave VMEM issue
// counts per step are identical to R11, so the verified vmcnt(2)/vmcnt(6)
// derivations carry over. Merges: pass-1 sum via 128B LDS exchange; pass-2
// ctx partial via 16KB LDS exchange (attnw kv-halves are disjoint per group).
// LDS 80KB -> 2 blocks/CU x 8 waves = 16 waves/CU (TLP unchanged vs R11:
// only chain length differs — clean A/B on the chain theory).
__global__ __launch_bounds__(512, 4) void attn_k(const u16* __restrict__ Q,
                                                 const u16* __restrict__ Kg,
                                                 const u16* __restrict__ Vt,
                                                 float* __restrict__ attnw,
                                                 u16* __restrict__ ctx) {
  __shared__ __align__(16) u16 Klds[2][3][64 * 64];
  __shared__ __align__(16) u16 Vlds[2][2][64 * 64];

  int tid = threadIdx.x;
  int w = tid >> 6, lane = tid & 63;
  int g = w >> 2, wq = w & 3;
  int r16 = lane & 15, c4 = lane >> 4;
  int id = blockIdx.x;
  int bh = id & 31, qt = id >> 5;
  int b = bh >> 4, h = bh & 15;
  int q0 = qt * 64 + wq * 16;
  int kvB = g << 10;

  const u16* Qp = Q + ((size_t)bh * 2048 + q0) * 64;
  const u16* Kp = Kg + (size_t)bh * 2048 * 64;
  const u16* Vp = Vt + (size_t)bh * 64 * 2048;

  bf16x8 qf0 = *(const bf16x8*)(Qp + (size_t)r16 * 64 + c4 * 8);
  bf16x8 qf1 = *(const bf16x8*)(Qp + (size_t)r16 * 64 + 32 + c4 * 8);

  int perm0 = ((r16 >> 2) << 3) + (r16 & 3);
  int srow0 = wq * 8 + (lane >> 3);
  int sc = lane & 7;

#define STAGE_K(bufi, kv)                                                      \
  {                                                                            \
    _Pragma("unroll") for (int i = 0; i < 2; ++i) {                            \
      int row = i * 32 + srow0;                                                \
      int ch = sc ^ fsw(row);                                                  \
      GLOAD_LDS16(Kp + (size_t)(kvB + ((kv) & 1023) + row) * 64 + ch * 8,      \
                  (u16*)&Klds[g][bufi][0] + wq * 512 + i * 2048);              \
    }                                                                          \
  }
#define STAGE_V(bufi, kv)                                                      \
  {                                                                            \
    _Pragma("unroll") for (int i = 0; i < 2; ++i) {                            \
      int row = i * 32 + srow0;                                                \
      int ch = sc ^ fsw(row);                                                  \
      GLOAD_LDS16(Vp + (size_t)row * 2048 + kvB + ((kv) & 1023) + ch * 8,      \
                  (u16*)&Vlds[g][bufi][0] + wq * 512 + i * 2048);              \
    }                                                                          \
  }
#define LDSF(base, row, chunk)                                                 \
  (*(const bf16x8*)((base) + (row) * 64 + (((chunk) ^ fsw(row)) << 3)))
#define WAIT_BAR(n)                                                            \
  {                                                                            \
    asm volatile("s_waitcnt vmcnt(" #n ")" ::: "memory");                      \
    __builtin_amdgcn_s_barrier();                                              \
  }

  // ---------------- pass 1: row sums of exp2(S) over this group's kv half ---
  float sum = 0.f;
  STAGE_K(0, 0);
  STAGE_K(1, 64);
  WAIT_BAR(2);  // K(0) done; K(1) in flight
  {
    int wbuf = 2, rbuf = 0;
    for (int kv0 = 0; kv0 < 1024; kv0 += 64) {
      STAGE_K(wbuf, kv0 + 128);
      const u16* Kb = &Klds[g][rbuf][0];
#pragma unroll
      for (int s = 0; s < 2; ++s) {
        int ra = s * 32 + perm0;
        bf16x8 k00 = LDSF(Kb, ra, c4);
        bf16x8 k01 = LDSF(Kb, ra, c4 + 4);
        bf16x8 k10 = LDSF(Kb, ra + 4, c4);
        bf16x8 k11 = LDSF(Kb, ra + 4, c4 + 4);
        f32x4 s0 = {}, s1 = {};
        __builtin_amdgcn_s_setprio(1);
        s0 = mfma16(k00, qf0, s0);
        s0 = mfma16(k01, qf1, s0);
        s1 = mfma16(k10, qf0, s1);
        s1 = mfma16(k11, qf1, s1);
        __builtin_amdgcn_s_setprio(0);
#pragma unroll
        for (int r = 0; r < 4; ++r)
          sum += __builtin_amdgcn_exp2f(s0[r]) + __builtin_amdgcn_exp2f(s1[r]);
      }
      WAIT_BAR(2);  // retire K(t+1); keep K(t+2) in flight
      wbuf = (wbuf == 2) ? 0 : wbuf + 1;
      rbuf = (rbuf == 2) ? 0 : rbuf + 1;
    }
  }
  sum += __shfl_xor(sum, 16, 64);
  sum += __shfl_xor(sum, 32, 64);

  // cross-group sum merge (Vlds unused in pass 1; syncthreads drains DMA tails)
  float* redbuf = (float*)&Vlds[0][0][0];
  __syncthreads();
  if (lane < 16) redbuf[(g * 4 + wq) * 16 + lane] = sum;
  __syncthreads();
  float stot = redbuf[(0 * 4 + wq) * 16 + r16] + redbuf[(1 * 4 + wq) * 16 + r16];
  float nls = -__log2f(stot);
  __syncthreads();  // all reads done before Vlds is re-staged in pass 2

  // ---------------- pass 2: P write + ctx partial over this kv half --------
  f32x4 o[4] = {};
  float* ap = attnw + ((size_t)bh * 2048 + q0 + r16) * 2048 + kvB;
  STAGE_V(0, 0);
  STAGE_K(0, 0);
  STAGE_K(1, 64);
  WAIT_BAR(2);  // V(0)+K(0) done; K(1) in flight
  {
    int wbuf = 2, rbuf = 0;
    int t = 0;
    for (int kv0 = 0; kv0 < 1024; kv0 += 64, ++t) {
      STAGE_V((t + 1) & 1, kv0 + 64);  // V(t+1), issued before K so it's older
      STAGE_K(wbuf, kv0 + 128);
      const u16* Kb = &Klds[g][rbuf][0];
      const u16* Vb = &Vlds[g][t & 1][0];
#pragma unroll
      for (int s = 0; s < 2; ++s) {
        int ra = s * 32 + perm0;
        bf16x8 k00 = LDSF(Kb, ra, c4);
        bf16x8 k01 = LDSF(Kb, ra, c4 + 4);
        bf16x8 k10 = LDSF(Kb, ra + 4, c4);
        bf16x8 k11 = LDSF(Kb, ra + 4, c4 + 4);
        f32x4 s0 = {}, s1 = {};
        __builtin_amdgcn_s_setprio(1);
        s0 = mfma16(k00, qf0, s0);
        s0 = mfma16(k01, qf1, s0);
        s1 = mfma16(k10, qf0, s1);
        s1 = mfma16(k11, qf1, s1);
        __builtin_amdgcn_s_setprio(0);
        f32x4 p0, p1;
#pragma unroll
        for (int r = 0; r < 4; ++r) {
          p0[r] = __builtin_amdgcn_exp2f(s0[r] + nls);
          p1[r] = __builtin_amdgcn_exp2f(s1[r] + nls);
        }
        u32x4 pk;
        pk[0] = pk2(p0[0], p0[1]);
        pk[1] = pk2(p0[2], p0[3]);
        pk[2] = pk2(p1[0], p1[1]);
        pk[3] = pk2(p1[2], p1[3]);
        bf16x8 pf = __builtin_bit_cast(bf16x8, pk);
        bf16x8 v0 = LDSF(Vb, 0 * 16 + r16, s * 4 + c4);
        bf16x8 v1 = LDSF(Vb, 1 * 16 + r16, s * 4 + c4);
        bf16x8 v2 = LDSF(Vb, 2 * 16 + r16, s * 4 + c4);
        bf16x8 v3 = LDSF(Vb, 3 * 16 + r16, s * 4 + c4);
        __builtin_amdgcn_s_setprio(1);
        o[0] = mfma16(pf, v0, o[0]);
        o[1] = mfma16(pf, v1, o[1]);
        o[2] = mfma16(pf, v2, o[2]);
        o[3] = mfma16(pf, v3, o[3]);
        __builtin_amdgcn_s_setprio(0);
        int kvc = kv0 + s * 32 + c4 * 8;
        *(f32x4*)(ap + kvc) = p0;
        *(f32x4*)(ap + kvc + 4) = p1;
      }
      WAIT_BAR(6);  // retire K(t+1)+V(t+1)+stores(t-1); keep K(t+2)+stores(t)
      wbuf = (wbuf == 2) ? 0 : wbuf + 1;
      rbuf = (rbuf == 2) ? 0 : rbuf + 1;
    }
  }

  // cross-group ctx merge: group 1 parks its partial in LDS, group 0 adds
  __syncthreads();  // drains tail DMAs + stores; Klds free for reuse
  float* cbuf = (float*)&Klds[0][0][0];  // 16 KB
  if (g == 1) {
#pragma unroll
    for (int dt = 0; dt < 4; ++dt)
      *(f32x4*)&cbuf[(wq * 64 + lane) * 16 + dt * 4] = o[dt];
  }
  __syncthreads();
  if (g == 0) {
#pragma unroll
    for (int dt = 0; dt < 4; ++dt) {
      f32x4 o1 = *(const f32x4*)&cbuf[(wq * 64 + lane) * 16 + dt * 4];
#pragma unroll
      for (int r = 0; r < 4; ++r)
        ctx[((size_t)(b * 2048 + q0 + c4 * 4 + r)) * 1024 + h * 64 + dt * 16 +
            r16] = f2b(o[dt][r] + o1[r]);
    }
  }
#undef STAGE_K
#undef STAGE_V
#undef LDSF
#undef WAIT_BAR
}

// ---------------- LayerNorm over last dim (1024), wave per row ----------------
__global__ __launch_bounds__(256) void ln_k(const float* __restrict__ Y,
                                            const float* __restrict__ gamma,
                                            const float* __restrict__ beta,
                                            float* __restrict__ out) {
  int row = blockIdx.x * 4 + (threadIdx.x >> 6);
  int lane = threadIdx.x & 63;
  const float* yr = Y + (size_t)row * 1024;
  float4 v[4];
  float sum = 0.f, sq = 0.f;
#pragma unroll
  for (int i = 0; i < 4; ++i) {
    v[i] = *(const float4*)(yr + i * 256 + lane * 4);
    sum += v[i].x + v[i].y + v[i].z + v[i].w;
    sq += v[i].x * v[i].x + v[i].y * v[i].y + v[i].z * v[i].z + v[i].w * v[i].w;
  }
#pragma unroll
  for (int m = 1; m < 64; m <<= 1) {
    sum += __shfl_xor(sum, m, 64);
    sq += __shfl_xor(sq, m, 64);
  }
  float mu = sum * (1.f / 1024.f);
  float var = sq * (1.f / 1024.f) - mu * mu;
  float rs = rsqrtf(var + 1e-5f);
  float* orow = out + (size_t)row * 1024;
#pragma unroll
  for (int i = 0; i < 4; ++i) {
    int c = i * 256 + lane * 4;
    float4 g = *(const float4*)(gamma + c);
    float4 be = *(const float4*)(beta + c);
    float4 o;
    o.x = (v[i].x - mu) * rs * g.x + be.x;
    o.y = (v[i].y - mu) * rs * g.y + be.y;
    o.z = (v[i].z - mu) * rs * g.z + be.z;
    o.w = (v[i].w - mu) * rs * g.w + be.w;
    *(float4*)(orow + c) = o;
  }
}

extern "C" void kernel_launch(void* const* d_in, const int* in_sizes, int n_in,
                              void* d_out, int out_size, void* d_ws,
                              size_t ws_size, hipStream_t stream) {
  const float* x = (const float*)d_in[0];
  const float* enc = (const float*)d_in[1];
  const float* Wq = (const float*)d_in[2];
  const float* bq = (const float*)d_in[3];
  const float* Wk = (const float*)d_in[4];
  const float* bk = (const float*)d_in[5];
  const float* Wv = (const float*)d_in[6];
  const float* bv = (const float*)d_in[7];
  const float* Wo = (const float*)d_in[8];
  const float* bo = (const float*)d_in[9];
  const float* gamma = (const float*)d_in[10];
  const float* beta = (const float*)d_in[11];

  float* out = (float*)d_out;
  float* attnw = out + (size_t)4194304;  // 2*2048*1024

  char* ws = (char*)d_ws;
  u16* xb = (u16*)(ws + (size_t)0);
  u16* eb = (u16*)(ws + ((size_t)8 << 20));
  u16* Wqb = (u16*)(ws + ((size_t)16 << 20));
  u16* Wkb = (u16*)(ws + ((size_t)18 << 20));
  u16* Wvb = (u16*)(ws + ((size_t)20 << 20));
  u16* Wob = (u16*)(ws + ((size_t)22 << 20));
  u16* Qws = (u16*)(ws + ((size_t)24 << 20));
  u16* Kws = (u16*)(ws + ((size_t)32 << 20));
  u16* Vt = (u16*)(ws + ((size_t)48 << 20));
  u16* ctx = (u16*)(ws + ((size_t)40 << 20));
  float* Yws = (float*)(ws + (size_t)0);  // reuse xb/eb (dead after gemms)

  cvt_bf16<<<dim3(1024), 256, 0, stream>>>(x, xb, 1048576);
  cvt_bf16<<<dim3(1024), 256, 0, stream>>>(enc, eb, 1048576);
  cvt_w4<<<dim3(256, 4), 256, 0, stream>>>(Wq, Wk, Wv, Wo, Wqb, Wkb, Wvb, Wob);

  gemm_qkv3<<<dim3(8, 32, 3), 256, 0, stream>>>(xb, eb, Wqb, Wkb, Wvb, bq, bk,
                                                bv, Qws, Kws, Vt);

  attn_k<<<dim3(1024), 512, 0, stream>>>(Qws, Kws, Vt, attnw, ctx);

  gemm_out<<<dim3(8, 32), 256, 0, stream>>>(ctx, Wob, bo, x, Yws);

  ln_k<<<dim3(1024), 256, 0, stream>>>(Yws, gamma, beta, out);
}